// Round 14
// baseline (137.787 us; speedup 1.0000x reference)
//
#include <hip/hip_runtime.h>
#include <math.h>

#define BB 32
#define CC 512
#define NN 4096
#define EMB 1024
#define NH 16
#define GNORM 0.017683882565766149f   // 1/(2*pi*9)

// d_out layout (floats): values | pos | batch | attention | penalty
#define OFF_POS   (BB*NH*EMB)             // 524288
#define OFF_BATCH (OFF_POS + BB*NH*2)     // 525312
#define OFF_ATTN  (OFF_BATCH + BB*NH)     // 525824
#define OFF_PEN   (OFF_ATTN + BB*NN*NH)   // 2622976

// ---------------- Kernel 1: x_mean[b,c] = mean over N of x[b,c,:] ----------------
__global__ __launch_bounds__(256) void k_mean(const float* __restrict__ x,
                                              float* __restrict__ xmean) {
    const size_t row = blockIdx.x;            // b*CC + c
    const int t = threadIdx.x;
    const float4* xr = (const float4*)(x + row * NN);
    float s = 0.f;
#pragma unroll
    for (int k = 0; k < 4; ++k) {
        float4 v = xr[t + 256 * k];
        s += (v.x + v.y) + (v.z + v.w);
    }
#pragma unroll
    for (int off = 32; off > 0; off >>= 1) s += __shfl_down(s, off, 64);
    __shared__ float ps[4];
    if ((t & 63) == 0) ps[t >> 6] = s;
    __syncthreads();
    if (t == 0) xmean[row] = (ps[0] + ps[1] + ps[2] + ps[3]) * (1.0f / NN);
}

// ---------------- Kernel 2a: hid[b][e] = silu(w1[e,:] . xmean[b,:] + b1[e]) ----------------
__global__ __launch_bounds__(256) void k_mlp_h(const float* __restrict__ xmean,
                                               const float* __restrict__ w1,
                                               const float* __restrict__ b1,
                                               float* __restrict__ hid) {
    const int b = blockIdx.x >> 3;
    const int e = (blockIdx.x & 7) * 128 + (threadIdx.x >> 1);
    const int seg = threadIdx.x & 1;
    const int t = threadIdx.x;
    __shared__ __align__(16) float xm[CC];
    xm[t]       = xmean[b * CC + t];
    xm[t + 256] = xmean[b * CC + t + 256];
    __syncthreads();
    const float4* wr = (const float4*)(w1 + (size_t)e * CC + seg * 256);
    const float4* xv = (const float4*)(xm + seg * 256);
    float4 a4 = make_float4(0.f, 0.f, 0.f, 0.f);
#pragma unroll 8
    for (int c4 = 0; c4 < 64; ++c4) {
        float4 w = wr[c4]; float4 xx = xv[c4];
        a4.x += w.x * xx.x; a4.y += w.y * xx.y; a4.z += w.z * xx.z; a4.w += w.w * xx.w;
    }
    float acc = (a4.x + a4.y) + (a4.z + a4.w);
    acc += __shfl_down(acc, 1, 2);
    if (seg == 0) {
        acc += b1[e];
        hid[(size_t)b * EMB + e] = acc / (1.f + expf(-acc));   // silu
    }
}

// ---------------- Kernel 2b: pos + separable Gaussian tables + pen ----------------
__global__ __launch_bounds__(256) void k_pos(const float* __restrict__ hid,
                                             const float* __restrict__ w2,
                                             const float* __restrict__ b2,
                                             float* __restrict__ out,
                                             float* __restrict__ gxT,
                                             float* __restrict__ gyT,
                                             float* __restrict__ pen) {
    const int b = blockIdx.x;
    const int t = threadIdx.x;
    __shared__ __align__(16) float hl[EMB];
    __shared__ float pp[2 * NH];
#pragma unroll
    for (int k = 0; k < 4; ++k) hl[t + 256 * k] = hid[(size_t)b * EMB + t + 256 * k];
    __syncthreads();
    // stage 1: pos
    const int o = t >> 3;          // 0..31
    const int seg = t & 7;         // 8-way split of E
    const float4* wr = (const float4*)(w2 + (size_t)o * EMB + seg * 128);
    const float4* hv = (const float4*)(hl + seg * 128);
    float acc = 0.f;
#pragma unroll
    for (int e4 = 0; e4 < 32; ++e4) {
        float4 w = wr[e4]; float4 hh = hv[e4];
        acc += w.x * hh.x + w.y * hh.y + w.z * hh.z + w.w * hh.w;
    }
    acc += __shfl_down(acc, 4, 64);
    acc += __shfl_down(acc, 2, 64);
    acc += __shfl_down(acc, 1, 64);
    if (seg == 0) {
        acc += b2[o];
        float p = 31.f / (1.f + expf(-acc));
        out[OFF_POS + b * 2 * NH + o] = p;
        pp[o] = p;
    }
    __syncthreads();
    // stage 2: tables gx[h][i], gy[h][j] + pen = norm * sum(gx) * sum(gy)
    const int h = t >> 4;          // 0..15
    const int kk = t & 15;         // 0..15, each covers 4 i
    const float px = pp[2 * h], py = pp[2 * h + 1];
    float sgx = 0.f, sgy = 0.f;
    float4 vx, vy;
#pragma unroll
    for (int r = 0; r < 4; ++r) {
        const float fi = (float)(4 * kk + r);
        float dx = fi - px, dy = fi - py;
        float gx = expf(dx * dx * (-1.f / 18.f));
        float gy = expf(dy * dy * (-1.f / 18.f));
        (&vx.x)[r] = gx; (&vy.x)[r] = gy;
        sgx += gx; sgy += gy;
    }
    *(float4*)(gxT + ((size_t)b * NH + h) * 64 + 4 * kk) = vx;
    *(float4*)(gyT + ((size_t)b * NH + h) * 64 + 4 * kk) = vy;
#pragma unroll
    for (int off = 8; off > 0; off >>= 1) {
        sgx += __shfl_down(sgx, off, 16);
        sgy += __shfl_down(sgy, off, 16);
    }
    if (kk == 0) pen[b * NH + h] = GNORM * sgx * sgy;
}

// ---------------- Kernel 3: S + fused attention-slice write (head-split waves) ----------------
// x-stream truncated at i >= 48: pos <= 31 => gx(i>=48) <= exp(-17^2/18) ~ 4e-8 (negligible).
__global__ __launch_bounds__(256) void k_S11(const float* __restrict__ x,
                                             const float* __restrict__ gxT,
                                             const float* __restrict__ gyT,
                                             float* __restrict__ S,
                                             float* __restrict__ out) {
    // XCD swizzle: cluster the 64 same-b blocks onto one XCD (table L2 locality)
    const int hwid = blockIdx.x;                 // 0..2047
    const int wgid = (hwid & 7) * 256 + (hwid >> 3);
    const int b  = 31 - (wgid >> 6);             // reversed traversal (L3 tail chase)
    const int cs = wgid & 63;                    // channel-slice AND n-slice (i row)
    const int c0 = cs * 8;
    const int t = threadIdx.x;
    const int w = t >> 6, lane = t & 63;
    const int h0 = (w & 1) * 8;                  // this wave's 8 heads
    const int cbase = c0 + (w >> 1) * 4;         // this wave's 4 channels

    __shared__ __align__(16) float gxL[NH][64];  // 4 KB
    __shared__ __align__(16) float gyL[NH][64];  // 4 KB
    ((float4*)gxL)[t] = ((const float4*)(gxT + (size_t)b * NH * 64))[t];
    ((float4*)gyL)[t] = ((const float4*)(gyT + (size_t)b * NH * 64))[t];
    __syncthreads();

    // fused attention slice: attn[b][cs*64+q][h] = GNORM * gx[h][cs] * gy[h][q]
    {
        const int q = t >> 2, hh = (t & 3) * 4;
        float4 v;
        v.x = GNORM * gxL[hh + 0][cs] * gyL[hh + 0][q];
        v.y = GNORM * gxL[hh + 1][cs] * gyL[hh + 1][q];
        v.z = GNORM * gxL[hh + 2][cs] * gyL[hh + 2][q];
        v.w = GNORM * gxL[hh + 3][cs] * gyL[hh + 3][q];
        ((float4*)(out + OFF_ATTN + ((size_t)b * NN + cs * 64) * NH))[t] = v;
    }

    const int jj = (lane & 15) * 4;              // this lane's j (f4-aligned)
    const int isub = lane >> 4;                  // row offset within 256-n chunk

    float acc[4][8];
#pragma unroll
    for (int i = 0; i < 4; ++i)
#pragma unroll
        for (int h = 0; h < 8; ++h) acc[i][h] = 0.f;

    const float* xb = x + ((size_t)b * CC + cbase) * NN + 4 * lane;

#pragma unroll 1
    for (int nc = 0; nc < 12; ++nc) {            // i < 48 only (gx negligible beyond)
        const int n0 = nc * 256;
        const int i0 = nc * 4 + isub;            // this lane's i
        float4 xv[4];
#pragma unroll
        for (int i = 0; i < 4; ++i)
            xv[i] = *(const float4*)(xb + (size_t)i * NN + n0);
#pragma unroll
        for (int h = 0; h < 8; ++h) {
            const float gx = gxL[h0 + h][i0];
            const float4 g = *(const float4*)&gyL[h0 + h][jj];
            const float ax = gx * g.x, ay = gx * g.y, az = gx * g.z, aw = gx * g.w;
#pragma unroll
            for (int i = 0; i < 4; ++i)
                acc[i][h] += ax * xv[i].x + ay * xv[i].y + az * xv[i].z + aw * xv[i].w;
        }
    }
    // cross-lane reduction over n
#pragma unroll
    for (int i = 0; i < 4; ++i)
#pragma unroll
        for (int h = 0; h < 8; ++h) {
            float s = acc[i][h];
#pragma unroll
            for (int off = 32; off > 0; off >>= 1) s += __shfl_down(s, off, 64);
            acc[i][h] = s;
        }
    if (lane == 0) {
#pragma unroll
        for (int i = 0; i < 4; ++i)
#pragma unroll
            for (int h = 0; h < 8; ++h)
                S[((size_t)b * NH + h0 + h) * CC + cbase + i] = GNORM * acc[i][h];
    }
}

// ---------------- Kernel 4: values = S @ wv^T + pen*bv (64x64 tile, 4x4 reg tile) ----------------
__global__ __launch_bounds__(256) void k_gemm(const float* __restrict__ S,
                                              const float* __restrict__ wv,
                                              const float* __restrict__ bv,
                                              const float* __restrict__ pen,
                                              float* __restrict__ out) {
    const int t = threadIdx.x;
    if (blockIdx.x == 0 && blockIdx.y == 0) {    // fused k_final
        float s = 0.f;
#pragma unroll
        for (int r = 0; r < 2; ++r) {
            const int i = t + 256 * r;
            float d = pen[i] - 1.f;
            s += d * d;
            out[OFF_BATCH + i] = (float)(i >> 4);
        }
#pragma unroll
        for (int off = 32; off > 0; off >>= 1) s += __shfl_down(s, off, 64);
        __shared__ float ps[4];
        if ((t & 63) == 0) ps[t >> 6] = s;
        __syncthreads();
        if (t == 0) out[OFF_PEN] = (ps[0] + ps[1] + ps[2] + ps[3]) * (1.f / 512.f);
    }
    const int m0 = blockIdx.x * 64;   // over B*NH = 512 (8 blocks)
    const int n0 = blockIdx.y * 64;   // over EMB = 1024 (16 blocks)
    const int tx = t & 15, ty = t >> 4;
    __shared__ __align__(16) float As[64][36];   // pad 36: 16B-aligned rows, <=2-way banks
    __shared__ __align__(16) float Bs[64][36];
    float acc[4][4];
#pragma unroll
    for (int mi = 0; mi < 4; ++mi)
#pragma unroll
        for (int ni = 0; ni < 4; ++ni) acc[mi][ni] = 0.f;
    const int lr = t >> 3, lc = (t & 7) * 4;
    for (int k0 = 0; k0 < CC; k0 += 32) {
        {
            *(float4*)&As[lr][lc]      = *(const float4*)(S  + (size_t)(m0 + lr) * CC + k0 + lc);
            *(float4*)&As[32 + lr][lc] = *(const float4*)(S  + (size_t)(m0 + 32 + lr) * CC + k0 + lc);
            *(float4*)&Bs[lr][lc]      = *(const float4*)(wv + (size_t)(n0 + lr) * CC + k0 + lc);
            *(float4*)&Bs[32 + lr][lc] = *(const float4*)(wv + (size_t)(n0 + 32 + lr) * CC + k0 + lc);
        }
        __syncthreads();
#pragma unroll
        for (int k4 = 0; k4 < 32; k4 += 4) {
            float4 a[4], bb[4];
#pragma unroll
            for (int mi = 0; mi < 4; ++mi) a[mi] = *(const float4*)&As[ty + 16 * mi][k4];
#pragma unroll
            for (int ni = 0; ni < 4; ++ni) bb[ni] = *(const float4*)&Bs[tx + 16 * ni][k4];
#pragma unroll
            for (int mi = 0; mi < 4; ++mi)
#pragma unroll
                for (int ni = 0; ni < 4; ++ni)
                    acc[mi][ni] += a[mi].x * bb[ni].x + a[mi].y * bb[ni].y
                                 + a[mi].z * bb[ni].z + a[mi].w * bb[ni].w;
        }
        __syncthreads();
    }
#pragma unroll
    for (int mi = 0; mi < 4; ++mi) {
        const int m = m0 + ty + 16 * mi;
        const float pm = pen[m];
#pragma unroll
        for (int ni = 0; ni < 4; ++ni) {
            const int nn = n0 + tx + 16 * ni;
            out[(size_t)m * EMB + nn] = acc[mi][ni] + pm * bv[nn];
        }
    }
}

extern "C" void kernel_launch(void* const* d_in, const int* in_sizes, int n_in,
                              void* d_out, int out_size, void* d_ws, size_t ws_size,
                              hipStream_t stream) {
    const float* x  = (const float*)d_in[0];
    const float* w1 = (const float*)d_in[1];
    const float* b1 = (const float*)d_in[2];
    const float* w2 = (const float*)d_in[3];
    const float* b2 = (const float*)d_in[4];
    const float* wv = (const float*)d_in[5];
    const float* bv = (const float*)d_in[6];
    float* out = (float*)d_out;

    float* xmean = (float*)d_ws;            // 16384
    float* pen   = xmean + BB * CC;         // 512
    float* S     = pen + BB * NH;           // 262144
    float* hid   = S + BB * NH * CC;        // 32768
    float* gxT   = hid + BB * EMB;          // 32768
    float* gyT   = gxT + BB * NH * 64;      // 32768

    k_mean<<<BB * CC, 256, 0, stream>>>(x, xmean);
    k_mlp_h<<<BB * 8, 256, 0, stream>>>(xmean, w1, b1, hid);
    k_pos<<<BB, 256, 0, stream>>>(hid, w2, b2, out, gxT, gyT, pen);
    k_S11<<<2048, 256, 0, stream>>>(x, gxT, gyT, S, out);
    k_gemm<<<dim3(8, 16), 256, 0, stream>>>(S, wv, bv, pen, out);
}

// Round 15
// 120.122 us; speedup vs baseline: 1.1471x; 1.1471x over previous
//
#include <hip/hip_runtime.h>
#include <math.h>

#define BB 32
#define CC 512
#define NN 4096
#define EMB 1024
#define NH 16
#define GNORM 0.017683882565766149f   // 1/(2*pi*9)

// d_out layout (floats): values | pos | batch | attention | penalty
#define OFF_POS   (BB*NH*EMB)             // 524288
#define OFF_BATCH (OFF_POS + BB*NH*2)     // 525312
#define OFF_ATTN  (OFF_BATCH + BB*NH)     // 525824
#define OFF_PEN   (OFF_ATTN + BB*NN*NH)   // 2622976

// ---------------- Kernel 1: x_mean[b,c] = mean over N of x[b,c,:] ----------------
__global__ __launch_bounds__(256) void k_mean(const float* __restrict__ x,
                                              float* __restrict__ xmean) {
    const size_t row = blockIdx.x;            // b*CC + c
    const int t = threadIdx.x;
    const float4* xr = (const float4*)(x + row * NN);
    float s = 0.f;
#pragma unroll
    for (int k = 0; k < 4; ++k) {
        float4 v = xr[t + 256 * k];
        s += (v.x + v.y) + (v.z + v.w);
    }
#pragma unroll
    for (int off = 32; off > 0; off >>= 1) s += __shfl_down(s, off, 64);
    __shared__ float ps[4];
    if ((t & 63) == 0) ps[t >> 6] = s;
    __syncthreads();
    if (t == 0) xmean[row] = (ps[0] + ps[1] + ps[2] + ps[3]) * (1.0f / NN);
}

// ---------------- Kernel 2a: hid[b][e] = silu(w1[e,:] . xmean[b,:] + b1[e]) ----------------
__global__ __launch_bounds__(256) void k_mlp_h(const float* __restrict__ xmean,
                                               const float* __restrict__ w1,
                                               const float* __restrict__ b1,
                                               float* __restrict__ hid) {
    const int b = blockIdx.x >> 3;
    const int e = (blockIdx.x & 7) * 128 + (threadIdx.x >> 1);
    const int seg = threadIdx.x & 1;
    const int t = threadIdx.x;
    __shared__ __align__(16) float xm[CC];
    xm[t]       = xmean[b * CC + t];
    xm[t + 256] = xmean[b * CC + t + 256];
    __syncthreads();
    const float4* wr = (const float4*)(w1 + (size_t)e * CC + seg * 256);
    const float4* xv = (const float4*)(xm + seg * 256);
    float4 a4 = make_float4(0.f, 0.f, 0.f, 0.f);
#pragma unroll 8
    for (int c4 = 0; c4 < 64; ++c4) {
        float4 w = wr[c4]; float4 xx = xv[c4];
        a4.x += w.x * xx.x; a4.y += w.y * xx.y; a4.z += w.z * xx.z; a4.w += w.w * xx.w;
    }
    float acc = (a4.x + a4.y) + (a4.z + a4.w);
    acc += __shfl_down(acc, 1, 2);
    if (seg == 0) {
        acc += b1[e];
        hid[(size_t)b * EMB + e] = acc / (1.f + expf(-acc));   // silu
    }
}

// ---------------- Kernel 2b: pos + separable Gaussian tables + pen ----------------
__global__ __launch_bounds__(256) void k_pos(const float* __restrict__ hid,
                                             const float* __restrict__ w2,
                                             const float* __restrict__ b2,
                                             float* __restrict__ out,
                                             float* __restrict__ gxT,
                                             float* __restrict__ gyT,
                                             float* __restrict__ pen) {
    const int b = blockIdx.x;
    const int t = threadIdx.x;
    __shared__ __align__(16) float hl[EMB];
    __shared__ float pp[2 * NH];
#pragma unroll
    for (int k = 0; k < 4; ++k) hl[t + 256 * k] = hid[(size_t)b * EMB + t + 256 * k];
    __syncthreads();
    // stage 1: pos
    const int o = t >> 3;          // 0..31
    const int seg = t & 7;         // 8-way split of E
    const float4* wr = (const float4*)(w2 + (size_t)o * EMB + seg * 128);
    const float4* hv = (const float4*)(hl + seg * 128);
    float acc = 0.f;
#pragma unroll
    for (int e4 = 0; e4 < 32; ++e4) {
        float4 w = wr[e4]; float4 hh = hv[e4];
        acc += w.x * hh.x + w.y * hh.y + w.z * hh.z + w.w * hh.w;
    }
    acc += __shfl_down(acc, 4, 64);
    acc += __shfl_down(acc, 2, 64);
    acc += __shfl_down(acc, 1, 64);
    if (seg == 0) {
        acc += b2[o];
        float p = 31.f / (1.f + expf(-acc));
        out[OFF_POS + b * 2 * NH + o] = p;
        pp[o] = p;
    }
    __syncthreads();
    // stage 2: tables gx[h][i], gy[h][j] + pen = norm * sum(gx) * sum(gy)
    const int h = t >> 4;          // 0..15
    const int kk = t & 15;         // 0..15, each covers 4 i
    const float px = pp[2 * h], py = pp[2 * h + 1];
    float sgx = 0.f, sgy = 0.f;
    float4 vx, vy;
#pragma unroll
    for (int r = 0; r < 4; ++r) {
        const float fi = (float)(4 * kk + r);
        float dx = fi - px, dy = fi - py;
        float gx = expf(dx * dx * (-1.f / 18.f));
        float gy = expf(dy * dy * (-1.f / 18.f));
        (&vx.x)[r] = gx; (&vy.x)[r] = gy;
        sgx += gx; sgy += gy;
    }
    *(float4*)(gxT + ((size_t)b * NH + h) * 64 + 4 * kk) = vx;
    *(float4*)(gyT + ((size_t)b * NH + h) * 64 + 4 * kk) = vy;
#pragma unroll
    for (int off = 8; off > 0; off >>= 1) {
        sgx += __shfl_down(sgx, off, 16);
        sgy += __shfl_down(sgy, off, 16);
    }
    if (kk == 0) pen[b * NH + h] = GNORM * sgx * sgy;
}

// ---------------- Kernel 3: S + fused attention-slice write (head-split waves) ----------------
// x-stream truncated at i >= 48 (pos <= 31 => gx negligible) AND per-chunk wave-uniform
// skip when all 8 heads' gx < 1e-8 for this wave's i-range (saves the x loads).
__global__ __launch_bounds__(256) void k_S12(const float* __restrict__ x,
                                             const float* __restrict__ gxT,
                                             const float* __restrict__ gyT,
                                             float* __restrict__ S,
                                             float* __restrict__ out) {
    // XCD swizzle: cluster the 64 same-b blocks onto one XCD (table L2 locality)
    const int hwid = blockIdx.x;                 // 0..2047
    const int wgid = (hwid & 7) * 256 + (hwid >> 3);
    const int b  = 31 - (wgid >> 6);             // reversed traversal (L3 tail chase)
    const int cs = wgid & 63;                    // channel-slice AND n-slice (i row)
    const int c0 = cs * 8;
    const int t = threadIdx.x;
    const int w = t >> 6, lane = t & 63;
    const int h0 = (w & 1) * 8;                  // this wave's 8 heads
    const int cbase = c0 + (w >> 1) * 4;         // this wave's 4 channels

    __shared__ __align__(16) float gxL[NH][64];  // 4 KB
    __shared__ __align__(16) float gyL[NH][64];  // 4 KB
    ((float4*)gxL)[t] = ((const float4*)(gxT + (size_t)b * NH * 64))[t];
    ((float4*)gyL)[t] = ((const float4*)(gyT + (size_t)b * NH * 64))[t];
    __syncthreads();

    // fused attention slice: attn[b][cs*64+q][h] = GNORM * gx[h][cs] * gy[h][q]
    {
        const int q = t >> 2, hh = (t & 3) * 4;
        float4 v;
        v.x = GNORM * gxL[hh + 0][cs] * gyL[hh + 0][q];
        v.y = GNORM * gxL[hh + 1][cs] * gyL[hh + 1][q];
        v.z = GNORM * gxL[hh + 2][cs] * gyL[hh + 2][q];
        v.w = GNORM * gxL[hh + 3][cs] * gyL[hh + 3][q];
        ((float4*)(out + OFF_ATTN + ((size_t)b * NN + cs * 64) * NH))[t] = v;
    }

    const int jj = (lane & 15) * 4;              // this lane's j (f4-aligned)
    const int isub = lane >> 4;                  // row offset within 256-n chunk

    float acc[4][8];
#pragma unroll
    for (int i = 0; i < 4; ++i)
#pragma unroll
        for (int h = 0; h < 8; ++h) acc[i][h] = 0.f;

    const float* xb = x + ((size_t)b * CC + cbase) * NN + 4 * lane;

#pragma unroll 1
    for (int nc = 0; nc < 12; ++nc) {            // i < 48 only
        const int n0 = nc * 256;
        const int i0 = nc * 4 + isub;            // this lane's i
        float gxv[8];
        float gmax = 0.f;
#pragma unroll
        for (int h = 0; h < 8; ++h) {
            gxv[h] = gxL[h0 + h][i0];
            gmax = fmaxf(gmax, gxv[h]);
        }
        if (!__any(gmax > 1e-8f)) continue;      // wave-uniform: all heads dead here
        float4 xv[4];
#pragma unroll
        for (int i = 0; i < 4; ++i)
            xv[i] = *(const float4*)(xb + (size_t)i * NN + n0);
#pragma unroll
        for (int h = 0; h < 8; ++h) {
            const float4 g = *(const float4*)&gyL[h0 + h][jj];
            const float ax = gxv[h] * g.x, ay = gxv[h] * g.y,
                        az = gxv[h] * g.z, aw = gxv[h] * g.w;
#pragma unroll
            for (int i = 0; i < 4; ++i)
                acc[i][h] += ax * xv[i].x + ay * xv[i].y + az * xv[i].z + aw * xv[i].w;
        }
    }
    // cross-lane reduction over n
#pragma unroll
    for (int i = 0; i < 4; ++i)
#pragma unroll
        for (int h = 0; h < 8; ++h) {
            float s = acc[i][h];
#pragma unroll
            for (int off = 32; off > 0; off >>= 1) s += __shfl_down(s, off, 64);
            acc[i][h] = s;
        }
    if (lane == 0) {
#pragma unroll
        for (int i = 0; i < 4; ++i)
#pragma unroll
            for (int h = 0; h < 8; ++h)
                S[((size_t)b * NH + h0 + h) * CC + cbase + i] = GNORM * acc[i][h];
    }
}

// ---------------- Kernel 4: values = S @ wv^T + pen*bv (32x64 tile, float4-k LDS, pad 36) ----------------
__global__ __launch_bounds__(256) void k_gemm(const float* __restrict__ S,
                                              const float* __restrict__ wv,
                                              const float* __restrict__ bv,
                                              const float* __restrict__ pen,
                                              float* __restrict__ out) {
    const int t = threadIdx.x;
    if (blockIdx.x == 0 && blockIdx.y == 0) {    // fused k_final
        float s = 0.f;
#pragma unroll
        for (int r = 0; r < 2; ++r) {
            const int i = t + 256 * r;
            float d = pen[i] - 1.f;
            s += d * d;
            out[OFF_BATCH + i] = (float)(i >> 4);
        }
#pragma unroll
        for (int off = 32; off > 0; off >>= 1) s += __shfl_down(s, off, 64);
        __shared__ float ps[4];
        if ((t & 63) == 0) ps[t >> 6] = s;
        __syncthreads();
        if (t == 0) out[OFF_PEN] = (ps[0] + ps[1] + ps[2] + ps[3]) * (1.f / 512.f);
    }
    const int m0 = blockIdx.x * 32;   // over B*NH = 512
    const int n0 = blockIdx.y * 64;   // over EMB = 1024
    const int tx = t & 15, ty = t >> 4;
    __shared__ __align__(16) float As[32][36];   // pad 36: 16B-aligned rows, <=2-way banks
    __shared__ __align__(16) float Bs[64][36];
    float acc[2][4];
#pragma unroll
    for (int mi = 0; mi < 2; ++mi)
#pragma unroll
        for (int ni = 0; ni < 4; ++ni) acc[mi][ni] = 0.f;
    const int lr = t >> 3, lc = (t & 7) * 4;
    for (int k0 = 0; k0 < CC; k0 += 32) {
        {
            *(float4*)&As[lr][lc]      = *(const float4*)(S  + (size_t)(m0 + lr) * CC + k0 + lc);
            *(float4*)&Bs[lr][lc]      = *(const float4*)(wv + (size_t)(n0 + lr) * CC + k0 + lc);
            *(float4*)&Bs[32 + lr][lc] = *(const float4*)(wv + (size_t)(n0 + 32 + lr) * CC + k0 + lc);
        }
        __syncthreads();
#pragma unroll
        for (int k4 = 0; k4 < 32; k4 += 4) {
            float4 a0 = *(const float4*)&As[ty][k4];
            float4 a1 = *(const float4*)&As[ty + 16][k4];
#pragma unroll
            for (int ni = 0; ni < 4; ++ni) {
                float4 bb = *(const float4*)&Bs[tx + 16 * ni][k4];
                acc[0][ni] += a0.x * bb.x + a0.y * bb.y + a0.z * bb.z + a0.w * bb.w;
                acc[1][ni] += a1.x * bb.x + a1.y * bb.y + a1.z * bb.z + a1.w * bb.w;
            }
        }
        __syncthreads();
    }
#pragma unroll
    for (int mi = 0; mi < 2; ++mi) {
        const int m = m0 + ty + 16 * mi;
        const float pm = pen[m];
#pragma unroll
        for (int ni = 0; ni < 4; ++ni) {
            const int nn = n0 + tx + 16 * ni;
            out[(size_t)m * EMB + nn] = acc[mi][ni] + pm * bv[nn];
        }
    }
}

extern "C" void kernel_launch(void* const* d_in, const int* in_sizes, int n_in,
                              void* d_out, int out_size, void* d_ws, size_t ws_size,
                              hipStream_t stream) {
    const float* x  = (const float*)d_in[0];
    const float* w1 = (const float*)d_in[1];
    const float* b1 = (const float*)d_in[2];
    const float* w2 = (const float*)d_in[3];
    const float* b2 = (const float*)d_in[4];
    const float* wv = (const float*)d_in[5];
    const float* bv = (const float*)d_in[6];
    float* out = (float*)d_out;

    float* xmean = (float*)d_ws;            // 16384
    float* pen   = xmean + BB * CC;         // 512
    float* S     = pen + BB * NH;           // 262144
    float* hid   = S + BB * NH * CC;        // 32768
    float* gxT   = hid + BB * EMB;          // 32768
    float* gyT   = gxT + BB * NH * 64;      // 32768

    k_mean<<<BB * CC, 256, 0, stream>>>(x, xmean);
    k_mlp_h<<<BB * 8, 256, 0, stream>>>(xmean, w1, b1, hid);
    k_pos<<<BB, 256, 0, stream>>>(hid, w2, b2, out, gxT, gyT, pen);
    k_S12<<<2048, 256, 0, stream>>>(x, gxT, gyT, S, out);
    k_gemm<<<dim3(16, 16), 256, 0, stream>>>(S, wv, bv, pen, out);
}